// Round 1
// baseline (594.887 us; speedup 1.0000x reference)
//
#include <hip/hip_runtime.h>

// HistogramLoss on MI355X.
// Phase 1: tiled Gram-matrix (F F^T) over upper-triangular 128x128 tile pairs,
//          fused soft-histogram binning into LDS, flushed to global accumulators.
// Phase 2: tiny finalize kernel: normalize, cumsum, dot -> scalar loss.

#define NN   8192
#define DD   256
#define BM   128
#define BK   32
#define BMP  132          // padded LDS leading dim (multiple of 4 for b128 alignment)
#define TS   151          // histogram bins actually reachable for s in [-1,1]
#define NREP 8            // LDS histogram replicas (conflict spreading)

__global__ __launch_bounds__(256, 2)
void gram_hist(const float* __restrict__ F,
               const int* __restrict__ cls,
               float* __restrict__ ghist,            // [2*TS]: [0,TS)=pos, [TS,2TS)=neg
               unsigned int* __restrict__ gposcnt) {
    __shared__ float As[BK][BMP];
    __shared__ float Bs[BK][BMP];
    __shared__ float hist[2][NREP][TS];
    __shared__ unsigned int s_pos;

    const int tid = threadIdx.x;

    // zero LDS histograms (first __syncthreads below makes this visible)
    for (int i = tid; i < 2 * NREP * TS; i += 256) ((float*)hist)[i] = 0.f;
    if (tid == 0) s_pos = 0u;

    // decode blockIdx -> (bi, bj) with bi <= bj (upper-triangular tile pairs)
    const int T = NN / BM;          // 64
    int rem = (int)blockIdx.x;
    int bi = 0;
    while (rem >= T - bi) { rem -= T - bi; ++bi; }
    const int bj = bi + rem;
    const int ibase = bi * BM, jbase = bj * BM;

    const int tr = tid >> 4;        // 0..15 (row group)
    const int tc = tid & 15;        // 0..15 (col group)

    float acc[8][8];
#pragma unroll
    for (int a = 0; a < 8; ++a)
#pragma unroll
        for (int b = 0; b < 8; ++b) acc[a][b] = 0.f;

    for (int kt = 0; kt < DD / BK; ++kt) {
        const int k0 = kt * BK;
        __syncthreads();
#pragma unroll
        for (int t = 0; t < 4; ++t) {
            const int f  = tid + t * 256;       // 0..1023
            const int r  = f >> 3;              // 0..127
            const int kq = (f & 7) << 2;        // 0,4,...,28
            const float4 va = *(const float4*)(F + (size_t)(ibase + r) * DD + k0 + kq);
            const float4 vb = *(const float4*)(F + (size_t)(jbase + r) * DD + k0 + kq);
            As[kq + 0][r] = va.x; As[kq + 1][r] = va.y;
            As[kq + 2][r] = va.z; As[kq + 3][r] = va.w;
            Bs[kq + 0][r] = vb.x; Bs[kq + 1][r] = vb.y;
            Bs[kq + 2][r] = vb.z; Bs[kq + 3][r] = vb.w;
        }
        __syncthreads();
#pragma unroll
        for (int k = 0; k < BK; ++k) {
            const float4 a0 = *(const float4*)&As[k][tr * 8];
            const float4 a1 = *(const float4*)&As[k][tr * 8 + 4];
            const float4 b0 = *(const float4*)&Bs[k][tc * 8];
            const float4 b1 = *(const float4*)&Bs[k][tc * 8 + 4];
            const float av[8] = {a0.x, a0.y, a0.z, a0.w, a1.x, a1.y, a1.z, a1.w};
            const float bv[8] = {b0.x, b0.y, b0.z, b0.w, b1.x, b1.y, b1.z, b1.w};
#pragma unroll
            for (int a = 0; a < 8; ++a)
#pragma unroll
                for (int b = 0; b < 8; ++b)
                    acc[a][b] = fmaf(av[a], bv[b], acc[a][b]);
        }
    }

    // ---- binning ----
    const float STEPF = (float)(2.0 / 150.0);
    int ci[8], cj[8];
#pragma unroll
    for (int a = 0; a < 8; ++a) ci[a] = cls[ibase + tr * 8 + a];
#pragma unroll
    for (int b = 0; b < 8; ++b) cj[b] = cls[jbase + tc * 8 + b];

    const int rep = tid & (NREP - 1);
    const bool offdiag = (bi != bj);
    unsigned int cpos = 0;

    __syncthreads();   // ensure all waves done with compute & hist zeros visible

#pragma unroll
    for (int a = 0; a < 8; ++a) {
        const int gi = ibase + tr * 8 + a;
#pragma unroll
        for (int b = 0; b < 8; ++b) {
            const int gj = jbase + tc * 8 + b;
            if (offdiag || gi < gj) {
                const float s    = acc[a][b];
                const float fs   = s / STEPF;
                const float fl   = floorf(fs);
                const float fv   = fl * STEPF;
                const float frac = (s - fv) / STEPF;
                int klow = (int)roundf((fv + 1.0f) / STEPF);
                klow = min(max(klow, 0), TS - 1);
                const int kup = min(klow + 1, TS - 1);
                const int p = (ci[a] == cj[b]) ? 0 : 1;
                cpos += (p == 0) ? 1u : 0u;
                atomicAdd(&hist[p][rep][klow], 1.0f - frac);
                atomicAdd(&hist[p][rep][kup], frac);
            }
        }
    }
    atomicAdd(&s_pos, cpos);
    __syncthreads();

    // flush LDS histogram to global accumulators
    for (int i = tid; i < 2 * TS; i += 256) {
        const int p = i / TS, bn = i % TS;
        float sum = 0.f;
#pragma unroll
        for (int r2 = 0; r2 < NREP; ++r2) sum += hist[p][r2][bn];
        if (sum != 0.f) atomicAdd(&ghist[i], sum);
    }
    if (tid == 0 && s_pos) atomicAdd(gposcnt, s_pos);
}

__global__ void finalize_loss(const float* __restrict__ ghist,
                              const unsigned int* __restrict__ gposcnt,
                              float* __restrict__ out) {
    if (threadIdx.x == 0 && blockIdx.x == 0) {
        const float P = 33550336.0f;               // 8192*8191/2
        float cpos = (float)(*gposcnt);
        float cneg = P - cpos;
        cpos = fmaxf(cpos, 1.f);
        cneg = fmaxf(cneg, 1.f);
        float cdf = 0.f, loss = 0.f;
        for (int b = 0; b < TS; ++b) {
            cdf  += ghist[b] / cpos;               // pos histogram -> inclusive cumsum
            loss += (ghist[TS + b] / cneg) * cdf;  // dot with neg histogram
        }
        out[0] = loss;
    }
}

extern "C" void kernel_launch(void* const* d_in, const int* in_sizes, int n_in,
                              void* d_out, int out_size, void* d_ws, size_t ws_size,
                              hipStream_t stream) {
    const float* F  = (const float*)d_in[0];
    const int* cls  = (const int*)d_in[1];

    float* ghist        = (float*)d_ws;
    unsigned int* gcnt  = (unsigned int*)((char*)d_ws + 2 * TS * sizeof(float));

    hipMemsetAsync(d_ws, 0, 2 * TS * sizeof(float) + sizeof(unsigned int), stream);

    const int T = NN / BM;                  // 64
    const int nblocks = T * (T + 1) / 2;    // 2080
    gram_hist<<<dim3(nblocks), dim3(256), 0, stream>>>(F, cls, ghist, gcnt);
    finalize_loss<<<1, 64, 0, stream>>>(ghist, gcnt, (float*)d_out);
}

// Round 2
// 480.507 us; speedup vs baseline: 1.2380x; 1.2380x over previous
//
#include <hip/hip_runtime.h>

// HistogramLoss on MI355X — MFMA path.
// Gram = F F^T with F split to bf16 hi/lo (3 MFMA passes: hh + hl + lh, fp32 acc,
// error ~1e-6), fused soft-histogram into LDS, flushed to global accumulators.
// Phase 2: tiny finalize kernel (normalize, cumsum, dot).

#define NN   8192
#define DD   256
#define BM   128
#define BK   32
#define TS   151
#define NREP 8
#define ROWB 80      // LDS row stride bytes: 32 bf16 = 64B data + 16B pad (conflict-free frag reads)

typedef __attribute__((ext_vector_type(8))) short short8;   // 8 bf16 (4 VGPRs)
typedef __attribute__((ext_vector_type(4))) float floatx4;

__device__ __forceinline__ unsigned int bf16_rtne(float x) {
    unsigned int u = __builtin_bit_cast(unsigned int, x);
    return (u + 0x7FFFu + ((u >> 16) & 1u)) >> 16;
}

__device__ __forceinline__ void split_store(unsigned char* hi_p, unsigned char* lo_p, float4 v) {
    unsigned int ax = __builtin_bit_cast(unsigned int, v.x);
    unsigned int ay = __builtin_bit_cast(unsigned int, v.y);
    unsigned int az = __builtin_bit_cast(unsigned int, v.z);
    unsigned int aw = __builtin_bit_cast(unsigned int, v.w);
    uint2 hi;
    hi.x = (ax >> 16) | (ay & 0xFFFF0000u);
    hi.y = (az >> 16) | (aw & 0xFFFF0000u);
    float lx = v.x - __builtin_bit_cast(float, ax & 0xFFFF0000u);
    float ly = v.y - __builtin_bit_cast(float, ay & 0xFFFF0000u);
    float lz = v.z - __builtin_bit_cast(float, az & 0xFFFF0000u);
    float lw = v.w - __builtin_bit_cast(float, aw & 0xFFFF0000u);
    uint2 lo;
    lo.x = bf16_rtne(lx) | (bf16_rtne(ly) << 16);
    lo.y = bf16_rtne(lz) | (bf16_rtne(lw) << 16);
    *(uint2*)hi_p = hi;
    *(uint2*)lo_p = lo;
}

__global__ __launch_bounds__(256, 2)
void gram_hist(const float* __restrict__ F,
               const int* __restrict__ cls,
               float* __restrict__ ghist,            // [2*TS]
               unsigned int* __restrict__ gposcnt) {
    __shared__ unsigned char smem[4 * BM * ROWB];    // Ahi|Alo|Bhi|Blo; hist overlaid after K-loop
    __shared__ unsigned int s_pos;

    const int tid  = threadIdx.x;
    const int lane = tid & 63;
    const int wave = tid >> 6;
    const int wr = wave >> 1, wc = wave & 1;         // 2x2 wave grid, 64x64 per wave
    const int r = lane & 15;                         // fragment row/col
    const int h = lane >> 4;                         // k-half selector 0..3

    // decode blockIdx -> upper-triangular tile pair (bi <= bj)
    const int T = NN / BM;                           // 64
    int rem = (int)blockIdx.x;
    int bi = 0;
    while (rem >= T - bi) { rem -= T - bi; ++bi; }
    const int bj = bi + rem;
    const int ibase = bi * BM, jbase = bj * BM;

    const unsigned AHI = 0, ALO = BM * ROWB, BHI = 2 * BM * ROWB, BLO = 3 * BM * ROWB;

    floatx4 acc[4][4];
    const floatx4 zf = {0.f, 0.f, 0.f, 0.f};
#pragma unroll
    for (int mi = 0; mi < 4; ++mi)
#pragma unroll
        for (int ni = 0; ni < 4; ++ni) acc[mi][ni] = zf;

    for (int kt = 0; kt < DD / BK; ++kt) {
        const int k0 = kt * BK;
        __syncthreads();
#pragma unroll
        for (int t = 0; t < 4; ++t) {
            const int idx = tid + t * 256;           // 0..1023
            const int row = idx >> 3, q = idx & 7;
            const unsigned off = (unsigned)row * ROWB + (unsigned)q * 8;
            const float4 va = *(const float4*)(F + (size_t)(ibase + row) * DD + k0 + q * 4);
            split_store(smem + AHI + off, smem + ALO + off, va);
            const float4 vb = *(const float4*)(F + (size_t)(jbase + row) * DD + k0 + q * 4);
            split_store(smem + BHI + off, smem + BLO + off, vb);
        }
        __syncthreads();

        short8 Ah[4], Al[4], Bh[4], Bl[4];
#pragma unroll
        for (int mi = 0; mi < 4; ++mi) {
            const unsigned o = (unsigned)(wr * 64 + mi * 16 + r) * ROWB + (unsigned)h * 16;
            Ah[mi] = *(const short8*)(smem + AHI + o);
            Al[mi] = *(const short8*)(smem + ALO + o);
        }
#pragma unroll
        for (int ni = 0; ni < 4; ++ni) {
            const unsigned o = (unsigned)(wc * 64 + ni * 16 + r) * ROWB + (unsigned)h * 16;
            Bh[ni] = *(const short8*)(smem + BHI + o);
            Bl[ni] = *(const short8*)(smem + BLO + o);
        }
#pragma unroll
        for (int mi = 0; mi < 4; ++mi)
#pragma unroll
            for (int ni = 0; ni < 4; ++ni) {
                acc[mi][ni] = __builtin_amdgcn_mfma_f32_16x16x32_bf16(Ah[mi], Bh[ni], acc[mi][ni], 0, 0, 0);
                acc[mi][ni] = __builtin_amdgcn_mfma_f32_16x16x32_bf16(Ah[mi], Bl[ni], acc[mi][ni], 0, 0, 0);
                acc[mi][ni] = __builtin_amdgcn_mfma_f32_16x16x32_bf16(Al[mi], Bh[ni], acc[mi][ni], 0, 0, 0);
            }
    }

    // ---- binning (hist overlaid onto tile LDS) ----
    __syncthreads();
    float* hist = (float*)smem;                      // [2][NREP][TS]
    for (int i = tid; i < 2 * NREP * TS; i += 256) hist[i] = 0.f;
    if (tid == 0) s_pos = 0u;
    __syncthreads();

    int ci[4][4], cj[4];
#pragma unroll
    for (int mi = 0; mi < 4; ++mi)
#pragma unroll
        for (int reg = 0; reg < 4; ++reg)
            ci[mi][reg] = cls[ibase + wr * 64 + mi * 16 + h * 4 + reg];
#pragma unroll
    for (int ni = 0; ni < 4; ++ni)
        cj[ni] = cls[jbase + wc * 64 + ni * 16 + r];

    const bool offdiag = (bi != bj);
    const int rep = lane & (NREP - 1);
    unsigned int cpos = 0;

#pragma unroll
    for (int mi = 0; mi < 4; ++mi)
#pragma unroll
        for (int ni = 0; ni < 4; ++ni)
#pragma unroll
            for (int reg = 0; reg < 4; ++reg) {
                const int gi = ibase + wr * 64 + mi * 16 + h * 4 + reg;
                const int gj = jbase + wc * 64 + ni * 16 + r;
                if (offdiag || gi < gj) {
                    const float x  = acc[mi][ni][reg] * 75.0f;   // 1/STEP = 75
                    const float fm = floorf(x);
                    const float frac = x - fm;
                    int k = (int)fm + 75;
                    k = min(max(k, 0), TS - 1);
                    const int ku = min(k + 1, TS - 1);
                    const int p = (ci[mi][reg] == cj[ni]) ? 0 : 1;
                    cpos += (p == 0) ? 1u : 0u;
                    atomicAdd(&hist[(p * NREP + rep) * TS + k], 1.0f - frac);
                    atomicAdd(&hist[(p * NREP + rep) * TS + ku], frac);
                }
            }
    atomicAdd(&s_pos, cpos);
    __syncthreads();

    for (int i = tid; i < 2 * TS; i += 256) {
        const int p = i / TS, bn = i % TS;
        float sum = 0.f;
#pragma unroll
        for (int r2 = 0; r2 < NREP; ++r2) sum += hist[(p * NREP + r2) * TS + bn];
        if (sum != 0.f) atomicAdd(&ghist[i], sum);
    }
    if (tid == 0 && s_pos) atomicAdd(gposcnt, s_pos);
}

__global__ void finalize_loss(const float* __restrict__ ghist,
                              const unsigned int* __restrict__ gposcnt,
                              float* __restrict__ out) {
    if (threadIdx.x == 0 && blockIdx.x == 0) {
        const float P = 33550336.0f;                 // 8192*8191/2
        float cpos = (float)(*gposcnt);
        float cneg = P - cpos;
        cpos = fmaxf(cpos, 1.f);
        cneg = fmaxf(cneg, 1.f);
        float cdf = 0.f, loss = 0.f;
        for (int b = 0; b < TS; ++b) {
            cdf  += ghist[b] / cpos;
            loss += (ghist[TS + b] / cneg) * cdf;
        }
        out[0] = loss;
    }
}

extern "C" void kernel_launch(void* const* d_in, const int* in_sizes, int n_in,
                              void* d_out, int out_size, void* d_ws, size_t ws_size,
                              hipStream_t stream) {
    const float* F = (const float*)d_in[0];
    const int* cls = (const int*)d_in[1];

    float* ghist       = (float*)d_ws;
    unsigned int* gcnt = (unsigned int*)((char*)d_ws + 2 * TS * sizeof(float));

    hipMemsetAsync(d_ws, 0, 2 * TS * sizeof(float) + sizeof(unsigned int), stream);

    const int T = NN / BM;                 // 64
    const int nblocks = T * (T + 1) / 2;   // 2080
    gram_hist<<<dim3(nblocks), dim3(256), 0, stream>>>(F, cls, ghist, gcnt);
    finalize_loss<<<1, 64, 0, stream>>>(ghist, gcnt, (float*)d_out);
}

// Round 3
// 164.893 us; speedup vs baseline: 3.6077x; 2.9140x over previous
//
#include <hip/hip_runtime.h>

// HistogramLoss on MI355X — MFMA Gram + integer-atomic soft histogram.
// Gram = F F^T with F split to bf16 hi/lo (3 MFMA passes: hh + hl + lh, fp32 acc).
// Soft histogram in 16.16 fixed point: w_lo + w_hi == 65536 exactly per pair,
// accumulated with NATIVE integer atomics (ds_add_u32 / global_atomic_add_x2)
// -- fp32 atomicAdd compiles to a CAS loop on gfx950 and serializes on the
// Gaussian-concentrated hot bins (that was ~440us of round 2's 470us).

#define NN   8192
#define DD   256
#define BM   128
#define BK   32
#define TS   151
#define NREP 8
#define ROWB 80      // LDS row stride bytes: 32 bf16 = 64B data + 16B pad

typedef __attribute__((ext_vector_type(8))) short short8;   // 8 bf16 (4 VGPRs)
typedef __attribute__((ext_vector_type(4))) float floatx4;

__device__ __forceinline__ unsigned int bf16_rtne(float x) {
    unsigned int u = __builtin_bit_cast(unsigned int, x);
    return (u + 0x7FFFu + ((u >> 16) & 1u)) >> 16;
}

__device__ __forceinline__ void split_store(unsigned char* hi_p, unsigned char* lo_p, float4 v) {
    unsigned int ax = __builtin_bit_cast(unsigned int, v.x);
    unsigned int ay = __builtin_bit_cast(unsigned int, v.y);
    unsigned int az = __builtin_bit_cast(unsigned int, v.z);
    unsigned int aw = __builtin_bit_cast(unsigned int, v.w);
    uint2 hi;
    hi.x = (ax >> 16) | (ay & 0xFFFF0000u);
    hi.y = (az >> 16) | (aw & 0xFFFF0000u);
    float lx = v.x - __builtin_bit_cast(float, ax & 0xFFFF0000u);
    float ly = v.y - __builtin_bit_cast(float, ay & 0xFFFF0000u);
    float lz = v.z - __builtin_bit_cast(float, az & 0xFFFF0000u);
    float lw = v.w - __builtin_bit_cast(float, aw & 0xFFFF0000u);
    uint2 lo;
    lo.x = bf16_rtne(lx) | (bf16_rtne(ly) << 16);
    lo.y = bf16_rtne(lz) | (bf16_rtne(lw) << 16);
    *(uint2*)hi_p = hi;
    *(uint2*)lo_p = lo;
}

__global__ __launch_bounds__(256, 2)
void gram_hist(const float* __restrict__ F,
               const int* __restrict__ cls,
               unsigned long long* __restrict__ ghist,   // [2*TS] fixed-point sums
               unsigned int* __restrict__ gposcnt) {
    __shared__ unsigned char smem[4 * BM * ROWB];        // Ahi|Alo|Bhi|Blo; hist overlaid later
    __shared__ unsigned int s_pos;

    const int tid  = threadIdx.x;
    const int lane = tid & 63;
    const int wave = tid >> 6;
    const int wr = wave >> 1, wc = wave & 1;             // 2x2 wave grid, 64x64 per wave
    const int r = lane & 15;
    const int h = lane >> 4;

    // decode blockIdx -> upper-triangular tile pair (bi <= bj)
    const int T = NN / BM;                               // 64
    int rem = (int)blockIdx.x;
    int bi = 0;
    while (rem >= T - bi) { rem -= T - bi; ++bi; }
    const int bj = bi + rem;
    const int ibase = bi * BM, jbase = bj * BM;

    const unsigned AHI = 0, ALO = BM * ROWB, BHI = 2 * BM * ROWB, BLO = 3 * BM * ROWB;

    floatx4 acc[4][4];
    const floatx4 zf = {0.f, 0.f, 0.f, 0.f};
#pragma unroll
    for (int mi = 0; mi < 4; ++mi)
#pragma unroll
        for (int ni = 0; ni < 4; ++ni) acc[mi][ni] = zf;

    for (int kt = 0; kt < DD / BK; ++kt) {
        const int k0 = kt * BK;
        __syncthreads();
#pragma unroll
        for (int t = 0; t < 4; ++t) {
            const int idx = tid + t * 256;
            const int row = idx >> 3, q = idx & 7;
            const unsigned off = (unsigned)row * ROWB + (unsigned)q * 8;
            const float4 va = *(const float4*)(F + (size_t)(ibase + row) * DD + k0 + q * 4);
            split_store(smem + AHI + off, smem + ALO + off, va);
            const float4 vb = *(const float4*)(F + (size_t)(jbase + row) * DD + k0 + q * 4);
            split_store(smem + BHI + off, smem + BLO + off, vb);
        }
        __syncthreads();

        short8 Ah[4], Al[4], Bh[4], Bl[4];
#pragma unroll
        for (int mi = 0; mi < 4; ++mi) {
            const unsigned o = (unsigned)(wr * 64 + mi * 16 + r) * ROWB + (unsigned)h * 16;
            Ah[mi] = *(const short8*)(smem + AHI + o);
            Al[mi] = *(const short8*)(smem + ALO + o);
        }
#pragma unroll
        for (int ni = 0; ni < 4; ++ni) {
            const unsigned o = (unsigned)(wc * 64 + ni * 16 + r) * ROWB + (unsigned)h * 16;
            Bh[ni] = *(const short8*)(smem + BHI + o);
            Bl[ni] = *(const short8*)(smem + BLO + o);
        }
#pragma unroll
        for (int mi = 0; mi < 4; ++mi)
#pragma unroll
            for (int ni = 0; ni < 4; ++ni) {
                acc[mi][ni] = __builtin_amdgcn_mfma_f32_16x16x32_bf16(Ah[mi], Bh[ni], acc[mi][ni], 0, 0, 0);
                acc[mi][ni] = __builtin_amdgcn_mfma_f32_16x16x32_bf16(Ah[mi], Bl[ni], acc[mi][ni], 0, 0, 0);
                acc[mi][ni] = __builtin_amdgcn_mfma_f32_16x16x32_bf16(Al[mi], Bh[ni], acc[mi][ni], 0, 0, 0);
            }
    }

    // ---- binning (u32 fixed-point hist overlaid onto tile LDS) ----
    __syncthreads();
    unsigned int* hist = (unsigned int*)smem;            // [2][NREP][TS]
    for (int i = tid; i < 2 * NREP * TS; i += 256) hist[i] = 0u;
    if (tid == 0) s_pos = 0u;
    __syncthreads();

    int ci[4][4], cj[4];
#pragma unroll
    for (int mi = 0; mi < 4; ++mi)
#pragma unroll
        for (int reg = 0; reg < 4; ++reg)
            ci[mi][reg] = cls[ibase + wr * 64 + mi * 16 + h * 4 + reg];
#pragma unroll
    for (int ni = 0; ni < 4; ++ni)
        cj[ni] = cls[jbase + wc * 64 + ni * 16 + r];

    const bool offdiag = (bi != bj);
    const int rep = lane & (NREP - 1);
    unsigned int cpos = 0;

#pragma unroll
    for (int mi = 0; mi < 4; ++mi)
#pragma unroll
        for (int ni = 0; ni < 4; ++ni)
#pragma unroll
            for (int reg = 0; reg < 4; ++reg) {
                const int gi = ibase + wr * 64 + mi * 16 + h * 4 + reg;
                const int gj = jbase + wc * 64 + ni * 16 + r;
                if (offdiag || gi < gj) {
                    const float x  = acc[mi][ni][reg] * 75.0f;   // 1/STEP = 75
                    const float fm = floorf(x);
                    float frac = x - fm;
                    frac = fminf(fmaxf(frac, 0.0f), 1.0f);
                    unsigned int q = (unsigned int)(frac * 65536.0f + 0.5f);
                    q = min(q, 65536u);
                    int k = (int)fm + 75;
                    k = min(max(k, 0), TS - 1);
                    const int ku = min(k + 1, TS - 1);
                    const int p = (ci[mi][reg] == cj[ni]) ? 0 : 1;
                    cpos += (p == 0) ? 1u : 0u;
                    atomicAdd(&hist[(p * NREP + rep) * TS + k], 65536u - q);
                    atomicAdd(&hist[(p * NREP + rep) * TS + ku], q);
                }
            }
    atomicAdd(&s_pos, cpos);
    __syncthreads();

    // flush LDS histogram (u32 partials) to global u64 accumulators
    for (int i = tid; i < 2 * TS; i += 256) {
        const int p = i / TS, bn = i % TS;
        unsigned long long sum = 0;
#pragma unroll
        for (int r2 = 0; r2 < NREP; ++r2) sum += hist[(p * NREP + r2) * TS + bn];
        if (sum) atomicAdd(&ghist[i], sum);
    }
    if (tid == 0 && s_pos) atomicAdd(gposcnt, s_pos);
}

__global__ void finalize_loss(const unsigned long long* __restrict__ ghist,
                              const unsigned int* __restrict__ gposcnt,
                              float* __restrict__ out) {
    if (threadIdx.x == 0 && blockIdx.x == 0) {
        const double P = 33550336.0;                     // 8192*8191/2
        const double SCALE = 65536.0;
        double cpos = (double)(*gposcnt);
        double cneg = P - cpos;
        if (cpos < 1.0) cpos = 1.0;
        if (cneg < 1.0) cneg = 1.0;
        double cdf = 0.0, loss = 0.0;
        for (int b = 0; b < TS; ++b) {
            cdf  += (double)ghist[b] / (SCALE * cpos);
            loss += ((double)ghist[TS + b] / (SCALE * cneg)) * cdf;
        }
        out[0] = (float)loss;
    }
}

extern "C" void kernel_launch(void* const* d_in, const int* in_sizes, int n_in,
                              void* d_out, int out_size, void* d_ws, size_t ws_size,
                              hipStream_t stream) {
    const float* F = (const float*)d_in[0];
    const int* cls = (const int*)d_in[1];

    unsigned long long* ghist = (unsigned long long*)d_ws;
    unsigned int* gcnt = (unsigned int*)((char*)d_ws + 2 * TS * sizeof(unsigned long long));

    hipMemsetAsync(d_ws, 0, 2 * TS * sizeof(unsigned long long) + sizeof(unsigned int), stream);

    const int T = NN / BM;                 // 64
    const int nblocks = T * (T + 1) / 2;   // 2080
    gram_hist<<<dim3(nblocks), dim3(256), 0, stream>>>(F, cls, ghist, gcnt);
    finalize_loss<<<1, 64, 0, stream>>>(ghist, gcnt, (float*)d_out);
}

// Round 4
// 132.740 us; speedup vs baseline: 4.4816x; 1.2422x over previous
//
#include <hip/hip_runtime.h>

// HistogramLoss on MI355X — round 4.
// Precompute F -> (Fhi, Flo) bf16 once (kills 64x-redundant per-block conversion),
// stage tiles with global_load_lds dwordx4 into linear [128][32] bf16 LDS
// (conflict-free by slot analysis), 3-pass MFMA (hh+hl+lh), and a packed-u64
// soft histogram: ONE ds_add_u64 per pair (lo32 -> bin k, hi32 -> bin k+1),
// NREP=16 replicas spread across all 16 LDS bank-pairs.

#define NN   8192
#define DD   256
#define BM   128
#define TS   151
#define NREP 16
#define TILEB (BM * 64)            // 8192 B per bf16 tile [128][32]

typedef __attribute__((ext_vector_type(8))) short short8;   // 8 bf16
typedef __attribute__((ext_vector_type(4))) float floatx4;

#define GLL16(g, l)                                                     \
    __builtin_amdgcn_global_load_lds(                                   \
        (const __attribute__((address_space(1))) void*)(g),             \
        (__attribute__((address_space(3))) void*)(l), 16, 0, 0)

__device__ __forceinline__ unsigned int bf16_rtne(float x) {
    unsigned int u = __builtin_bit_cast(unsigned int, x);
    return (u + 0x7FFFu + ((u >> 16) & 1u)) >> 16;
}

// ---------- phase 0: split f32 -> bf16 hi (trunc) + bf16 lo (rtne residual) ----------
__global__ __launch_bounds__(256)
void split_bf16(const float* __restrict__ F,
                unsigned int* __restrict__ fhi,      // as uint2[ N*D/4 ]
                unsigned int* __restrict__ flo) {
    const int i = blockIdx.x * 256 + threadIdx.x;    // one float4 per thread
    const float4 v = ((const float4*)F)[i];
    const unsigned ax = __builtin_bit_cast(unsigned, v.x);
    const unsigned ay = __builtin_bit_cast(unsigned, v.y);
    const unsigned az = __builtin_bit_cast(unsigned, v.z);
    const unsigned aw = __builtin_bit_cast(unsigned, v.w);
    uint2 hi;
    hi.x = (ax >> 16) | (ay & 0xFFFF0000u);
    hi.y = (az >> 16) | (aw & 0xFFFF0000u);
    const float lx = v.x - __builtin_bit_cast(float, ax & 0xFFFF0000u);
    const float ly = v.y - __builtin_bit_cast(float, ay & 0xFFFF0000u);
    const float lz = v.z - __builtin_bit_cast(float, az & 0xFFFF0000u);
    const float lw = v.w - __builtin_bit_cast(float, aw & 0xFFFF0000u);
    uint2 lo;
    lo.x = bf16_rtne(lx) | (bf16_rtne(ly) << 16);
    lo.y = bf16_rtne(lz) | (bf16_rtne(lw) << 16);
    ((uint2*)fhi)[i] = hi;
    ((uint2*)flo)[i] = lo;
}

// ---------- phase 1: Gram tiles + fused packed-u64 soft histogram ----------
__global__ __launch_bounds__(256, 3)
void gram_hist(const unsigned char* __restrict__ fhiB,
               const unsigned char* __restrict__ floB,
               const int* __restrict__ cls,
               unsigned long long* __restrict__ glo,    // [2*TS] sum of lo-weights
               unsigned long long* __restrict__ ghi) {  // [2*TS] sum of hi-weights (-> bin+1)
    __shared__ __align__(16) unsigned long long hist_s[2 * NREP * TS];  // 38656 B
    unsigned char* smem = (unsigned char*)hist_s;                        // staging overlay (32768 B)

    const int tid  = threadIdx.x;
    const int lane = tid & 63;
    const int wave = tid >> 6;
    const int wr = wave >> 1, wc = wave & 1;     // 2x2 wave grid, 64x64 per wave
    const int r = lane & 15;
    const int h = lane >> 4;

    // decode blockIdx -> upper-triangular tile pair (bi <= bj)
    const int T = NN / BM;                       // 64
    int rem = (int)blockIdx.x;
    int bi = 0;
    while (rem >= T - bi) { rem -= T - bi; ++bi; }
    const int bj = bi + rem;
    const int ibase = bi * BM, jbase = bj * BM;

    const unsigned AHI = 0, ALO = TILEB, BHI = 2 * TILEB, BLO = 3 * TILEB;

    // staging addresses: wave w stages rows [w*32, w*32+32) of each tile;
    // lane l covers row w*32 + i*16 + (l>>2), 16-byte column chunk (l&3).
    const int srow = lane >> 2;                  // 0..15
    const int scolb = (lane & 3) * 16;           // byte within 64-B row
    const unsigned oA0 = (unsigned)(ibase + wave * 32 + srow) * 512 + scolb;
    const unsigned oA1 = oA0 + 16 * 512;
    const unsigned oB0 = (unsigned)(jbase + wave * 32 + srow) * 512 + scolb;
    const unsigned oB1 = oB0 + 16 * 512;
    const unsigned ldsb = (unsigned)wave * 2048;

    floatx4 acc[4][4];
    const floatx4 zf = {0.f, 0.f, 0.f, 0.f};
#pragma unroll
    for (int mi = 0; mi < 4; ++mi)
#pragma unroll
        for (int ni = 0; ni < 4; ++ni) acc[mi][ni] = zf;

    for (int kt = 0; kt < DD / 32; ++kt) {
        const unsigned ko = (unsigned)kt * 64;   // byte step: 32 bf16
        __syncthreads();                         // prev compute done before overwrite
        GLL16(fhiB + oA0 + ko, smem + AHI + ldsb);
        GLL16(fhiB + oA1 + ko, smem + AHI + ldsb + 1024);
        GLL16(floB + oA0 + ko, smem + ALO + ldsb);
        GLL16(floB + oA1 + ko, smem + ALO + ldsb + 1024);
        GLL16(fhiB + oB0 + ko, smem + BHI + ldsb);
        GLL16(fhiB + oB1 + ko, smem + BHI + ldsb + 1024);
        GLL16(floB + oB0 + ko, smem + BLO + ldsb);
        GLL16(floB + oB1 + ko, smem + BLO + ldsb + 1024);
        __syncthreads();                         // compiler drains vmcnt before barrier

        short8 Ah[4], Al[4];
#pragma unroll
        for (int mi = 0; mi < 4; ++mi) {
            const unsigned o = (unsigned)(wr * 64 + mi * 16 + r) * 64 + (unsigned)h * 16;
            Ah[mi] = *(const short8*)(smem + AHI + o);
            Al[mi] = *(const short8*)(smem + ALO + o);
        }
#pragma unroll
        for (int ni = 0; ni < 4; ++ni) {
            const unsigned o = (unsigned)(wc * 64 + ni * 16 + r) * 64 + (unsigned)h * 16;
            const short8 Bh = *(const short8*)(smem + BHI + o);
            const short8 Bl = *(const short8*)(smem + BLO + o);
#pragma unroll
            for (int mi = 0; mi < 4; ++mi) {
                acc[mi][ni] = __builtin_amdgcn_mfma_f32_16x16x32_bf16(Ah[mi], Bh, acc[mi][ni], 0, 0, 0);
                acc[mi][ni] = __builtin_amdgcn_mfma_f32_16x16x32_bf16(Ah[mi], Bl, acc[mi][ni], 0, 0, 0);
                acc[mi][ni] = __builtin_amdgcn_mfma_f32_16x16x32_bf16(Al[mi], Bh, acc[mi][ni], 0, 0, 0);
            }
        }
    }

    // ---- binning: packed 16.16 fixed point, one ds_add_u64 per pair ----
    __syncthreads();                             // all frag reads done before overlay
#pragma unroll 4
    for (int i = tid; i < 2 * NREP * TS; i += 256) hist_s[i] = 0ull;
    __syncthreads();

    int ci[4][4], cj[4];
#pragma unroll
    for (int mi = 0; mi < 4; ++mi)
#pragma unroll
        for (int reg = 0; reg < 4; ++reg)
            ci[mi][reg] = cls[ibase + wr * 64 + mi * 16 + h * 4 + reg];
#pragma unroll
    for (int ni = 0; ni < 4; ++ni)
        cj[ni] = cls[jbase + wc * 64 + ni * 16 + r];

    const bool offdiag = (bi != bj);
    const int rep = lane & (NREP - 1);
    const float SC = 75.0f * 65536.0f;           // (s+1)*75 in 16.16 fixed point

#pragma unroll
    for (int mi = 0; mi < 4; ++mi)
#pragma unroll
        for (int ni = 0; ni < 4; ++ni)
#pragma unroll
            for (int reg = 0; reg < 4; ++reg) {
                const int gi = ibase + wr * 64 + mi * 16 + h * 4 + reg;
                const int gj = jbase + wc * 64 + ni * 16 + r;
                if (offdiag || gi < gj) {
                    int Yi = (int)fmaf(acc[mi][ni][reg], SC, SC);
                    Yi = min(max(Yi, 0), 150 * 65536);
                    const int k = Yi >> 16;
                    const unsigned q = (unsigned)Yi & 65535u;
                    const unsigned long long val =
                        ((unsigned long long)q << 32) | (unsigned long long)(65536u - q);
                    const int p = (ci[mi][reg] == cj[ni]) ? 0 : 1;
                    atomicAdd(&hist_s[(p * NREP + rep) * TS + k], val);
                }
            }
    __syncthreads();

    // flush: sum replicas (lo-sum <= 2^30 * ... total <= 16384*65536 = 2^30, no carry),
    // then split into global lo/hi accumulators.
    for (int i = tid; i < 2 * TS; i += 256) {
        const int p = i / TS, b = i - p * TS;
        unsigned long long s = 0;
#pragma unroll
        for (int r2 = 0; r2 < NREP; ++r2) s += hist_s[(p * NREP + r2) * TS + b];
        const unsigned long long lo = s & 0xFFFFFFFFull;
        const unsigned long long hi = s >> 32;
        if (lo) atomicAdd(&glo[i], lo);
        if (hi) atomicAdd(&ghi[i], hi);
    }
}

// ---------- phase 2: finalize ----------
__global__ void finalize_loss(const unsigned long long* __restrict__ glo,
                              const unsigned long long* __restrict__ ghi,
                              float* __restrict__ out) {
    if (threadIdx.x == 0 && blockIdx.x == 0) {
        const double P = 33550336.0;             // 8192*8191/2
        unsigned long long posmass = 0;
        for (int b = 0; b < TS; ++b) posmass += glo[b] + ghi[b];
        double cpos = (double)(posmass / 65536ull);   // exact: each pos pair adds 65536 total
        double cneg = P - cpos;
        if (cpos < 1.0) cpos = 1.0;
        if (cneg < 1.0) cneg = 1.0;
        const double np = 65536.0 * cpos, nn = 65536.0 * cneg;
        double cdf = 0.0, loss = 0.0;
        for (int b = 0; b < TS; ++b) {
            const double mp = (double)glo[b] + (b ? (double)ghi[b - 1] : 0.0);
            const double mn = (double)glo[TS + b] + (b ? (double)ghi[TS + b - 1] : 0.0);
            cdf  += mp / np;
            loss += (mn / nn) * cdf;
        }
        out[0] = (float)loss;
    }
}

// ================= fallback (round-3 kernel) if ws is too small =================
#define ROWB 80
#define NREPF 8

__device__ __forceinline__ void split_store_fb(unsigned char* hi_p, unsigned char* lo_p, float4 v) {
    unsigned ax = __builtin_bit_cast(unsigned, v.x), ay = __builtin_bit_cast(unsigned, v.y);
    unsigned az = __builtin_bit_cast(unsigned, v.z), aw = __builtin_bit_cast(unsigned, v.w);
    uint2 hi; hi.x = (ax >> 16) | (ay & 0xFFFF0000u); hi.y = (az >> 16) | (aw & 0xFFFF0000u);
    float lx = v.x - __builtin_bit_cast(float, ax & 0xFFFF0000u);
    float ly = v.y - __builtin_bit_cast(float, ay & 0xFFFF0000u);
    float lz = v.z - __builtin_bit_cast(float, az & 0xFFFF0000u);
    float lw = v.w - __builtin_bit_cast(float, aw & 0xFFFF0000u);
    uint2 lo; lo.x = bf16_rtne(lx) | (bf16_rtne(ly) << 16); lo.y = bf16_rtne(lz) | (bf16_rtne(lw) << 16);
    *(uint2*)hi_p = hi; *(uint2*)lo_p = lo;
}

__global__ __launch_bounds__(256, 2)
void gram_hist_fb(const float* __restrict__ F, const int* __restrict__ cls,
                  unsigned long long* __restrict__ ghist, unsigned int* __restrict__ gposcnt) {
    __shared__ unsigned char smem[4 * BM * ROWB];
    __shared__ unsigned int s_pos;
    const int tid = threadIdx.x, lane = tid & 63, wave = tid >> 6;
    const int wr = wave >> 1, wc = wave & 1, r = lane & 15, h = lane >> 4;
    const int T = NN / BM;
    int rem = (int)blockIdx.x; int bi = 0;
    while (rem >= T - bi) { rem -= T - bi; ++bi; }
    const int bj = bi + rem, ibase = bi * BM, jbase = bj * BM;
    const unsigned AHI = 0, ALO = BM * ROWB, BHI = 2 * BM * ROWB, BLO = 3 * BM * ROWB;
    floatx4 acc[4][4]; const floatx4 zf = {0.f,0.f,0.f,0.f};
    for (int mi = 0; mi < 4; ++mi) for (int ni = 0; ni < 4; ++ni) acc[mi][ni] = zf;
    for (int kt = 0; kt < DD / 32; ++kt) {
        const int k0 = kt * 32;
        __syncthreads();
        for (int t = 0; t < 4; ++t) {
            const int idx = tid + t * 256, row = idx >> 3, q = idx & 7;
            const unsigned off = (unsigned)row * ROWB + (unsigned)q * 8;
            split_store_fb(smem + AHI + off, smem + ALO + off,
                           *(const float4*)(F + (size_t)(ibase + row) * DD + k0 + q * 4));
            split_store_fb(smem + BHI + off, smem + BLO + off,
                           *(const float4*)(F + (size_t)(jbase + row) * DD + k0 + q * 4));
        }
        __syncthreads();
        short8 Ah[4], Al[4];
        for (int mi = 0; mi < 4; ++mi) {
            const unsigned o = (unsigned)(wr * 64 + mi * 16 + r) * ROWB + (unsigned)h * 16;
            Ah[mi] = *(const short8*)(smem + AHI + o); Al[mi] = *(const short8*)(smem + ALO + o);
        }
        for (int ni = 0; ni < 4; ++ni) {
            const unsigned o = (unsigned)(wc * 64 + ni * 16 + r) * ROWB + (unsigned)h * 16;
            const short8 Bh = *(const short8*)(smem + BHI + o);
            const short8 Bl = *(const short8*)(smem + BLO + o);
            for (int mi = 0; mi < 4; ++mi) {
                acc[mi][ni] = __builtin_amdgcn_mfma_f32_16x16x32_bf16(Ah[mi], Bh, acc[mi][ni], 0, 0, 0);
                acc[mi][ni] = __builtin_amdgcn_mfma_f32_16x16x32_bf16(Ah[mi], Bl, acc[mi][ni], 0, 0, 0);
                acc[mi][ni] = __builtin_amdgcn_mfma_f32_16x16x32_bf16(Al[mi], Bh, acc[mi][ni], 0, 0, 0);
            }
        }
    }
    __syncthreads();
    unsigned int* hist = (unsigned int*)smem;
    for (int i = tid; i < 2 * NREPF * TS; i += 256) hist[i] = 0u;
    if (tid == 0) s_pos = 0u;
    __syncthreads();
    int ci[4][4], cj[4];
    for (int mi = 0; mi < 4; ++mi) for (int reg = 0; reg < 4; ++reg)
        ci[mi][reg] = cls[ibase + wr * 64 + mi * 16 + h * 4 + reg];
    for (int ni = 0; ni < 4; ++ni) cj[ni] = cls[jbase + wc * 64 + ni * 16 + r];
    const bool offdiag = (bi != bj); const int rep = lane & (NREPF - 1);
    unsigned int cpos = 0;
    for (int mi = 0; mi < 4; ++mi) for (int ni = 0; ni < 4; ++ni) for (int reg = 0; reg < 4; ++reg) {
        const int gi = ibase + wr * 64 + mi * 16 + h * 4 + reg;
        const int gj = jbase + wc * 64 + ni * 16 + r;
        if (offdiag || gi < gj) {
            int Yi = (int)fmaf(acc[mi][ni][reg], 75.0f * 65536.0f, 75.0f * 65536.0f);
            Yi = min(max(Yi, 0), 150 * 65536);
            const int k = Yi >> 16; const unsigned q = (unsigned)Yi & 65535u;
            const int ku = min(k + 1, TS - 1);
            const int p = (ci[mi][reg] == cj[ni]) ? 0 : 1;
            cpos += (p == 0) ? 1u : 0u;
            atomicAdd(&hist[(p * NREPF + rep) * TS + k], 65536u - q);
            atomicAdd(&hist[(p * NREPF + rep) * TS + ku], q);
        }
    }
    atomicAdd(&s_pos, cpos);
    __syncthreads();
    for (int i = tid; i < 2 * TS; i += 256) {
        unsigned long long sum = 0;
        for (int r2 = 0; r2 < NREPF; ++r2) sum += hist[((i / TS) * NREPF + r2) * TS + (i % TS)];
        if (sum) atomicAdd(&ghist[i], sum);
    }
    if (tid == 0 && s_pos) atomicAdd(gposcnt, s_pos);
}

__global__ void finalize_fb(const unsigned long long* __restrict__ ghist,
                            const unsigned int* __restrict__ gposcnt, float* __restrict__ out) {
    if (threadIdx.x == 0 && blockIdx.x == 0) {
        const double P = 33550336.0, SCALE = 65536.0;
        double cpos = (double)(*gposcnt), cneg = P - cpos;
        if (cpos < 1.0) cpos = 1.0; if (cneg < 1.0) cneg = 1.0;
        double cdf = 0.0, loss = 0.0;
        for (int b = 0; b < TS; ++b) {
            cdf  += (double)ghist[b] / (SCALE * cpos);
            loss += ((double)ghist[TS + b] / (SCALE * cneg)) * cdf;
        }
        out[0] = (float)loss;
    }
}

// ================================ launch ================================
extern "C" void kernel_launch(void* const* d_in, const int* in_sizes, int n_in,
                              void* d_out, int out_size, void* d_ws, size_t ws_size,
                              hipStream_t stream) {
    const float* F = (const float*)d_in[0];
    const int* cls = (const int*)d_in[1];
    const int T = NN / BM;                     // 64
    const int nblocks = T * (T + 1) / 2;       // 2080

    const size_t FHALF = (size_t)NN * DD * 2;  // 4 MB per bf16 copy
    const size_t need = 2 * FHALF + 4 * TS * sizeof(unsigned long long) + 64;

    if (ws_size >= need) {
        unsigned int* fhi = (unsigned int*)d_ws;
        unsigned int* flo = (unsigned int*)((char*)d_ws + FHALF);
        unsigned long long* glo = (unsigned long long*)((char*)d_ws + 2 * FHALF);
        unsigned long long* ghi = glo + 2 * TS;
        hipMemsetAsync(glo, 0, 4 * TS * sizeof(unsigned long long), stream);
        split_bf16<<<dim3(NN * DD / 4 / 256), dim3(256), 0, stream>>>(F, fhi, flo);
        gram_hist<<<dim3(nblocks), dim3(256), 0, stream>>>(
            (const unsigned char*)fhi, (const unsigned char*)flo, cls, glo, ghi);
        finalize_loss<<<1, 64, 0, stream>>>(glo, ghi, (float*)d_out);
    } else {
        unsigned long long* ghist = (unsigned long long*)d_ws;
        unsigned int* gcnt = (unsigned int*)((char*)d_ws + 2 * TS * sizeof(unsigned long long));
        hipMemsetAsync(d_ws, 0, 2 * TS * sizeof(unsigned long long) + sizeof(unsigned int), stream);
        gram_hist_fb<<<dim3(nblocks), dim3(256), 0, stream>>>(F, cls, ghist, gcnt);
        finalize_fb<<<1, 64, 0, stream>>>(ghist, gcnt, (float*)d_out);
    }
}